// Round 12
// baseline (6568.583 us; speedup 1.0000x reference)
//
#include <hip/hip_runtime.h>
#include <math.h>

// ESBN: encoder (conv x3 + linear) + 64-step LSTM/memory scan. fp32.
// R12: scan re-associated as G = Gh + Gkx with ONE wait-free launch per step:
//   step blocks  (0..255):  authoritative step t from G(t); kx(t+1) stays in
//                           LDS -> Gkx(t+1) = kx @ Wih^T (K=65).
//   gates blocks (256..511): recompute h(t) redundantly (cheap elementwise),
//                           Gh(t+1) = h(t) @ Whh^T (K=512, XCD-pinned slice).
// All cross-block data crosses KERNEL BOUNDARIES only (no flags/fences).
// Encoder: conv1 + enc2(two-half c1 load) split, measured best.

__device__ __forceinline__ float sigm(float x) { return 1.0f / (1.0f + expf(-x)); }

// ---------------------------------------------------------------------------
// prep: transposed weights in ws.
//   WT [580][2048] (rows 0..64 w_ih^T, 65..576 w_hh^T, 577..579 zero),
//   bsum[2048], w1T[48][32], w2T[512][64], w3T[1024][64], ewT[256][64]
// ---------------------------------------------------------------------------
#define PREP_N (1187840 + 2048 + 1536 + 32768 + 65536 + 16384)
__global__ __launch_bounds__(256) void prep_kernel(
    const float* __restrict__ w_ih, const float* __restrict__ w_hh,
    const float* __restrict__ b_ih, const float* __restrict__ b_hh,
    const float* __restrict__ w1, const float* __restrict__ w2,
    const float* __restrict__ w3, const float* __restrict__ ew,
    float* __restrict__ WT, float* __restrict__ bsum,
    float* __restrict__ w1T, float* __restrict__ w2T,
    float* __restrict__ w3T, float* __restrict__ ewT)
{
  int i = blockIdx.x * 256 + threadIdx.x;
  if (i < 1187840) {
    const int r = i >> 11, c = i & 2047;
    float v;
    if (r < 65)       v = w_ih[(size_t)c * 65 + r];
    else if (r < 577) v = w_hh[(size_t)c * 512 + (r - 65)];
    else              v = 0.0f;
    WT[i] = v; return;
  }
  i -= 1187840;
  if (i < 2048) { bsum[i] = b_ih[i] + b_hh[i]; return; }
  i -= 2048;
  if (i < 1536) { const int r = i >> 5, oc = i & 31; w1T[i] = w1[oc * 48 + r]; return; }
  i -= 1536;
  if (i < 32768) { const int r = i >> 6, oc = i & 63; w2T[i] = w2[oc * 512 + r]; return; }
  i -= 32768;
  if (i < 65536) { const int r = i >> 6, oc = i & 63; w3T[i] = w3[oc * 1024 + r]; return; }
  i -= 65536;
  if (i < 16384) { const int k = i >> 6, d = i & 63; ewT[i] = ew[d * 256 + k]; return; }
}

// ---------------------------------------------------------------------------
// E1: conv1 (3->32, k4 s2, out 15x15, ReLU), one block per sample.
// ---------------------------------------------------------------------------
#define ENT 192
__global__ __launch_bounds__(ENT) void conv1_kernel(
    const float* __restrict__ images,
    const float* __restrict__ w1T, const float* __restrict__ b1,
    float* __restrict__ c1g, const int s0)
{
  __shared__ __align__(16) float buf[3072];
  const int bid = blockIdx.x;
  const int tid = threadIdx.x;
  {
    const float4* src = (const float4*)(images + (size_t)(s0 + bid) * 3072);
    float4* dst = (float4*)buf;
    for (int i = tid; i < 768; i += ENT) dst[i] = src[i];
  }
  __syncthreads();

  float* outp = c1g + (size_t)bid * 7680;
  for (int s = tid; s < 360; s += ENT) {
    const int ocg  = s & 7;
    const int pg   = s >> 3;
    const int row  = pg / 3;
    const int colg = pg - row * 3;
    const int ox0  = colg * 5;
    float acc[4][5];
    #pragma unroll
    for (int o = 0; o < 4; ++o) {
      const float bb = b1[ocg * 4 + o];
      #pragma unroll
      for (int p = 0; p < 5; ++p) acc[o][p] = bb;
    }
    #pragma unroll
    for (int ic = 0; ic < 3; ++ic) {
      #pragma unroll
      for (int ky = 0; ky < 4; ++ky) {
        const int y = 2 * row + ky;
        const float* ib = &buf[ic * 1024 + y * 32 + 2 * ox0];
        float v[12];
        #pragma unroll
        for (int i = 0; i < 6; ++i) { float2 t2 = *(const float2*)(ib + 2 * i); v[2*i] = t2.x; v[2*i+1] = t2.y; }
        float w_[4][4];
        #pragma unroll
        for (int kx = 0; kx < 4; ++kx)
          *(float4*)&w_[kx][0] = *(const float4*)(w1T + (ic * 16 + ky * 4 + kx) * 32 + ocg * 4);
        #pragma unroll
        for (int o = 0; o < 4; ++o)
          #pragma unroll
          for (int p = 0; p < 5; ++p)
            acc[o][p] += w_[0][o] * v[2*p] + w_[1][o] * v[2*p+1] + w_[2][o] * v[2*p+2] + w_[3][o] * v[2*p+3];
      }
    }
    #pragma unroll
    for (int o = 0; o < 4; ++o)
      #pragma unroll
      for (int p = 0; p < 5; ++p)
        outp[(ocg * 4 + o) * 240 + row * 16 + ox0 + p] = fmaxf(acc[o][p], 0.0f);
  }
}

// ---------------------------------------------------------------------------
// E2: conv2 + conv3 + linear; c1 loaded in TWO 16-ic halves (LDS 24.8 KB).
// ---------------------------------------------------------------------------
__global__ __launch_bounds__(ENT) void enc2_kernel(
    const float* __restrict__ c1g,
    const float* __restrict__ w2T, const float* __restrict__ b2,
    const float* __restrict__ w3T, const float* __restrict__ b3,
    const float* __restrict__ ewT, const float* __restrict__ eb,
    float* __restrict__ z_all, const int s0)
{
  __shared__ __align__(16) float c1h[3840];   // [16][240]
  __shared__ __align__(16) float buf[2368];   // [64][37]
  const int bid = blockIdx.x;
  const int tid = threadIdx.x;

  const int ocg = tid & 15;
  const int pg  = tid >> 4;
  const int row = pg >> 1;
  const int ox0 = (pg & 1) * 3;
  float acc2[4][3];
  #pragma unroll
  for (int o = 0; o < 4; ++o) {
    const float bb = b2[ocg * 4 + o];
    acc2[o][0] = bb; acc2[o][1] = bb; acc2[o][2] = bb;
  }

  for (int half = 0; half < 2; ++half) {
    {
      const float4* src = (const float4*)(c1g + (size_t)bid * 7680 + half * 3840);
      float4* dst = (float4*)c1h;
      for (int i = tid; i < 960; i += ENT) dst[i] = src[i];
    }
    __syncthreads();
    for (int icl = 0; icl < 16; ++icl) {
      #pragma unroll
      for (int ky = 0; ky < 4; ++ky) {
        const int y = 2 * row + ky;
        const float* ib = &c1h[icl * 240 + y * 16 + 2 * ox0];
        float v[8];
        #pragma unroll
        for (int i = 0; i < 4; ++i) { float2 t2 = *(const float2*)(ib + 2 * i); v[2*i] = t2.x; v[2*i+1] = t2.y; }
        float w_[4][4];
        #pragma unroll
        for (int kx = 0; kx < 4; ++kx)
          *(float4*)&w_[kx][0] = *(const float4*)(w2T + ((half * 16 + icl) * 16 + ky * 4 + kx) * 64 + ocg * 4);
        #pragma unroll
        for (int o = 0; o < 4; ++o)
          #pragma unroll
          for (int p = 0; p < 3; ++p)
            acc2[o][p] += w_[0][o] * v[2*p] + w_[1][o] * v[2*p+1] + w_[2][o] * v[2*p+2] + w_[3][o] * v[2*p+3];
      }
    }
    __syncthreads();
  }

  #pragma unroll
  for (int o = 0; o < 4; ++o)
    #pragma unroll
    for (int p = 0; p < 3; ++p)
      buf[(ocg * 4 + o) * 37 + row * 6 + ox0 + p] = fmaxf(acc2[o][p], 0.0f);
  __syncthreads();

  {
    const int oc = tid & 63;
    const int kc = tid >> 6;
    const int k0 = (kc * 256) / 3, k1 = ((kc + 1) * 256) / 3;
    float acc[4] = {0.f, 0.f, 0.f, 0.f};
    for (int it = k0; it < k1; ++it) {
      const int ic = it >> 2;
      const int ky = it & 3;
      float v[2][6];
      #pragma unroll
      for (int oy = 0; oy < 2; ++oy) {
        const float* ib = &buf[ic * 37 + (2 * oy + ky) * 6];
        #pragma unroll
        for (int i = 0; i < 3; ++i) { float2 t2 = *(const float2*)(ib + 2 * i); v[oy][2*i] = t2.x; v[oy][2*i+1] = t2.y; }
      }
      float w_[4];
      #pragma unroll
      for (int kx = 0; kx < 4; ++kx) w_[kx] = w3T[(ic * 16 + ky * 4 + kx) * 64 + oc];
      #pragma unroll
      for (int p = 0; p < 4; ++p) {
        const int oy = p >> 1, ox = p & 1;
        acc[p] += w_[0] * v[oy][2*ox] + w_[1] * v[oy][2*ox+1] + w_[2] * v[oy][2*ox+2] + w_[3] * v[oy][2*ox+3];
      }
    }
    #pragma unroll
    for (int p = 0; p < 4; ++p) c1h[kc * 260 + p * 64 + oc] = acc[p];
  }
  __syncthreads();

  for (int o = tid; o < 256; o += ENT) {
    const int oc = o >> 2, p = o & 3;
    c1h[1024 + o] = b3[oc] + c1h[p * 64 + oc] + c1h[260 + p * 64 + oc] + c1h[520 + p * 64 + oc];
  }
  __syncthreads();

  {
    const int d  = tid & 63;
    const int kc = tid >> 6;
    const int k0 = (kc * 256) / 3, k1 = ((kc + 1) * 256) / 3;
    float s = 0.0f;
    for (int k = k0; k < k1; ++k) s += ewT[k * 64 + d] * c1h[1024 + k];
    c1h[1536 + kc * 64 + d] = s;
  }
  __syncthreads();
  if (tid < 64) {
    z_all[(size_t)(s0 + bid) * 64 + tid] = eb[tid] + c1h[1536 + tid] + c1h[1600 + tid] + c1h[1664 + tid];
  }
}

// ---------------------------------------------------------------------------
// Monolithic encoder fallback (if ws can't hold c1g chunks).
// ---------------------------------------------------------------------------
__global__ __launch_bounds__(ENT) void encoder_kernel(
    const float* __restrict__ images,
    const float* __restrict__ w1T, const float* __restrict__ b1,
    const float* __restrict__ w2T, const float* __restrict__ b2,
    const float* __restrict__ w3T, const float* __restrict__ b3,
    const float* __restrict__ ewT, const float* __restrict__ eb,
    float* __restrict__ z_all)
{
  __shared__ __align__(16) float c1[7744];
  __shared__ __align__(16) float buf[3072];
  const int bid = blockIdx.x;
  const int tid = threadIdx.x;
  {
    const float4* src = (const float4*)(images + (size_t)bid * 3072);
    float4* dst = (float4*)buf;
    for (int i = tid; i < 768; i += ENT) dst[i] = src[i];
  }
  __syncthreads();
  for (int s = tid; s < 360; s += ENT) {
    const int ocg  = s & 7;
    const int pg   = s >> 3;
    const int row  = pg / 3;
    const int colg = pg - row * 3;
    const int ox0  = colg * 5;
    float acc[4][5];
    #pragma unroll
    for (int o = 0; o < 4; ++o) {
      const float bb = b1[ocg * 4 + o];
      #pragma unroll
      for (int p = 0; p < 5; ++p) acc[o][p] = bb;
    }
    #pragma unroll
    for (int ic = 0; ic < 3; ++ic) {
      #pragma unroll
      for (int ky = 0; ky < 4; ++ky) {
        const int y = 2 * row + ky;
        const float* ib = &buf[ic * 1024 + y * 32 + 2 * ox0];
        float v[12];
        #pragma unroll
        for (int i = 0; i < 6; ++i) { float2 t2 = *(const float2*)(ib + 2 * i); v[2*i] = t2.x; v[2*i+1] = t2.y; }
        float w_[4][4];
        #pragma unroll
        for (int kx = 0; kx < 4; ++kx)
          *(float4*)&w_[kx][0] = *(const float4*)(w1T + (ic * 16 + ky * 4 + kx) * 32 + ocg * 4);
        #pragma unroll
        for (int o = 0; o < 4; ++o)
          #pragma unroll
          for (int p = 0; p < 5; ++p)
            acc[o][p] += w_[0][o] * v[2*p] + w_[1][o] * v[2*p+1] + w_[2][o] * v[2*p+2] + w_[3][o] * v[2*p+3];
      }
    }
    #pragma unroll
    for (int o = 0; o < 4; ++o)
      #pragma unroll
      for (int p = 0; p < 5; ++p)
        c1[(ocg * 4 + o) * 242 + row * 16 + ox0 + p] = fmaxf(acc[o][p], 0.0f);
  }
  __syncthreads();
  {
    const int ocg = tid & 15;
    const int pg  = tid >> 4;
    const int row = pg >> 1;
    const int ox0 = (pg & 1) * 3;
    float acc[4][3];
    #pragma unroll
    for (int o = 0; o < 4; ++o) {
      const float bb = b2[ocg * 4 + o];
      acc[o][0] = bb; acc[o][1] = bb; acc[o][2] = bb;
    }
    for (int ic = 0; ic < 32; ++ic) {
      #pragma unroll
      for (int ky = 0; ky < 4; ++ky) {
        const int y = 2 * row + ky;
        const float* ib = &c1[ic * 242 + y * 16 + 2 * ox0];
        float v[8];
        #pragma unroll
        for (int i = 0; i < 4; ++i) { float2 t2 = *(const float2*)(ib + 2 * i); v[2*i] = t2.x; v[2*i+1] = t2.y; }
        float w_[4][4];
        #pragma unroll
        for (int kx = 0; kx < 4; ++kx)
          *(float4*)&w_[kx][0] = *(const float4*)(w2T + (ic * 16 + ky * 4 + kx) * 64 + ocg * 4);
        #pragma unroll
        for (int o = 0; o < 4; ++o)
          #pragma unroll
          for (int p = 0; p < 3; ++p)
            acc[o][p] += w_[0][o] * v[2*p] + w_[1][o] * v[2*p+1] + w_[2][o] * v[2*p+2] + w_[3][o] * v[2*p+3];
      }
    }
    __syncthreads();
    #pragma unroll
    for (int o = 0; o < 4; ++o)
      #pragma unroll
      for (int p = 0; p < 3; ++p)
        buf[(ocg * 4 + o) * 38 + row * 6 + ox0 + p] = fmaxf(acc[o][p], 0.0f);
  }
  __syncthreads();
  {
    const int oc = tid & 63;
    const int kc = tid >> 6;
    const int k0 = (kc * 256) / 3, k1 = ((kc + 1) * 256) / 3;
    float acc[4] = {0.f, 0.f, 0.f, 0.f};
    for (int it = k0; it < k1; ++it) {
      const int ic = it >> 2;
      const int ky = it & 3;
      float v[2][6];
      #pragma unroll
      for (int oy = 0; oy < 2; ++oy) {
        const float* ib = &buf[ic * 38 + (2 * oy + ky) * 6];
        #pragma unroll
        for (int i = 0; i < 3; ++i) { float2 t2 = *(const float2*)(ib + 2 * i); v[oy][2*i] = t2.x; v[oy][2*i+1] = t2.y; }
      }
      float w_[4];
      #pragma unroll
      for (int kx = 0; kx < 4; ++kx) w_[kx] = w3T[(ic * 16 + ky * 4 + kx) * 64 + oc];
      #pragma unroll
      for (int p = 0; p < 4; ++p) {
        const int oy = p >> 1, ox = p & 1;
        acc[p] += w_[0] * v[oy][2*ox] + w_[1] * v[oy][2*ox+1] + w_[2] * v[oy][2*ox+2] + w_[3] * v[oy][2*ox+3];
      }
    }
    #pragma unroll
    for (int p = 0; p < 4; ++p) c1[kc * 260 + p * 64 + oc] = acc[p];
  }
  __syncthreads();
  for (int o = tid; o < 256; o += ENT) {
    const int oc = o >> 2, p = o & 3;
    c1[1024 + o] = b3[oc] + c1[p * 64 + oc] + c1[260 + p * 64 + oc] + c1[520 + p * 64 + oc];
  }
  __syncthreads();
  {
    const int d  = tid & 63;
    const int kc = tid >> 6;
    const int k0 = (kc * 256) / 3, k1 = ((kc + 1) * 256) / 3;
    float s = 0.0f;
    for (int k = k0; k < k1; ++k) s += ewT[k * 64 + d] * c1[1024 + k];
    c1[1536 + kc * 64 + d] = s;
  }
  __syncthreads();
  if (tid < 64) {
    z_all[(size_t)bid * 64 + tid] = eb[tid] + c1[1536 + tid] + c1[1600 + tid] + c1[1664 + tid];
  }
}

// ---------------------------------------------------------------------------
// z-Gram: z_gram[b][t][n] = z_t . z_n
// ---------------------------------------------------------------------------
__global__ __launch_bounds__(256) void gram_kernel(
    const float* __restrict__ z_all, float* __restrict__ z_gram)
{
  const int b = blockIdx.x;
  const int tid = threadIdx.x;
  __shared__ float zsb[64 * 65];
  for (int i = tid; i < 4096; i += 256) {
    const int tt = i >> 6, d = i & 63;
    zsb[tt * 65 + d] = z_all[((size_t)tt * 256 + b) * 64 + d];
  }
  __syncthreads();
  const int n = tid & 63, tg = tid >> 6;
  for (int tt = tg; tt < 64; tt += 4) {
    float s = 0.0f;
    #pragma unroll
    for (int d = 0; d < 64; ++d) s += zsb[tt * 65 + d] * zsb[n * 65 + d];
    z_gram[((size_t)b * 64 + tt) * 64 + n] = s;
  }
}

// ---------------------------------------------------------------------------
// Wait-free pipelined scan step (64 launches, grid 512 x 256).
//  blocks 0..255  (step, b=bid): G(t)=Ghin+Gkin -> LSTM elementwise (Cout),
//    dots (kw->MkT[b] col t, y->out, g), softmax (z_gram), memory read ->
//    kx(t+1) in LDS -> Gkout[b] = kx @ WT[0..65). t==0: Gkout[b]=0.
//  blocks 256..511 (gates, g=bid-256, bt=g>>4, jt=g&15): recompute h(t) for
//    16 batches (elementwise, redundant), Ghout[slice] = h @ WT[65..577).
//    g%8==jt%8 pins each 256KB Whh slice to one XCD L2. t==63: skip.
// No intra-kernel cross-block deps: all producer->consumer edges cross the
// kernel boundary (stream order provides coherence on MI355X).
// ---------------------------------------------------------------------------
__global__ __launch_bounds__(256, 2) void scan_pipe_kernel(
    const int t,
    const float* __restrict__ Ghin, float* __restrict__ Ghout,
    const float* __restrict__ Gkin, float* __restrict__ Gkout,
    const float* __restrict__ Cin, float* __restrict__ Cout,
    const float* __restrict__ WT, const float* __restrict__ bsum,
    const float* __restrict__ z_gram, float* __restrict__ MkT,
    float* __restrict__ o_ptr,
    const float* __restrict__ out_w, const float* __restrict__ out_b,
    const float* __restrict__ gate_w, const float* __restrict__ gate_b,
    const float* __restrict__ key_w, const float* __restrict__ key_b,
    const float* __restrict__ conf_w, const float* __restrict__ conf_b)
{
  __shared__ __align__(16) float smem[9216];   // gates: hs2T[512][18]; step: scratch
  const int tid = threadIdx.x;
  const int bid = blockIdx.x;

  if (bid < 256) {
    // ===== step role, batch b =====
    const int b = bid;
    float* hs  = smem;          // 512
    float* wks = smem + 512;    // 64
    float* psum= smem + 576;    // 256
    float* sgp = smem + 832;    // 1
    float* kxp = smem + 833;    // 1
    float* kxs = smem + 840;    // 65

    // LSTM elementwise (authoritative): 2 j per thread
    {
      const float* ghp = Ghin + (size_t)b * 2048;
      const float* gkp = Gkin + (size_t)b * 2048;
      #pragma unroll
      for (int h2 = 0; h2 < 2; ++h2) {
        const int jj = tid + h2 * 256;
        const float gi = bsum[jj]        + ghp[jj]        + gkp[jj];
        const float gf = bsum[512 + jj]  + ghp[512 + jj]  + gkp[512 + jj];
        const float gg = bsum[1024 + jj] + ghp[1024 + jj] + gkp[1024 + jj];
        const float go = bsum[1536 + jj] + ghp[1536 + jj] + gkp[1536 + jj];
        const float c2 = sigm(gf) * Cin[(size_t)b * 512 + jj] + sigm(gi) * tanhf(gg);
        Cout[(size_t)b * 512 + jj] = c2;
        hs[jj] = sigm(go) * tanhf(c2);
      }
    }
    __syncthreads();

    // 69 dots: kw -> MkT[b] col t, y -> out, g -> sgp
    {
      const int lane = tid & 63, wv = tid >> 6;
      for (int d = wv; d < 69; d += 4) {
        const float* row = (d < 64) ? (key_w + (size_t)d * 512)
                         : (d < 68) ? (out_w + (size_t)(d - 64) * 512)
                                    : gate_w;
        float a = 0.0f;
        #pragma unroll
        for (int kk = 0; kk < 8; ++kk) a += hs[lane + kk * 64] * row[lane + kk * 64];
        #pragma unroll
        for (int m = 32; m > 0; m >>= 1) a += __shfl_xor(a, m);
        if (lane == 0) {
          if (d < 64)      MkT[(size_t)b * 4096 + d * 64 + t] = a + key_b[d];
          else if (d < 68) o_ptr[(size_t)t * 1024 + b * 4 + (d - 64)] = a + out_b[d - 64];
          else             *sgp = sigm(a + gate_b[0]);
        }
      }
    }
    __syncthreads();

    if (t == 0) {
      // kx(1) = 0 -> Gkx(1) = 0
      float4 z4; z4.x = 0.f; z4.y = 0.f; z4.z = 0.f; z4.w = 0.f;
      *(float4*)(Gkout + (size_t)b * 2048 + tid * 8) = z4;
      *(float4*)(Gkout + (size_t)b * 2048 + tid * 8 + 4) = z4;
      return;
    }

    // masked softmax + ck reduce
    if (tid < 64) {
      const int n = tid;
      const float sim = z_gram[((size_t)b * 64 + t) * 64 + n];
      const bool valid = (n < t);
      float mx = valid ? sim : -3.0e38f;
      #pragma unroll
      for (int m = 32; m > 0; m >>= 1) mx = fmaxf(mx, __shfl_xor(mx, m));
      const float p = valid ? expf(sim - mx) : 0.0f;
      float sum = p;
      #pragma unroll
      for (int m = 32; m > 0; m >>= 1) sum += __shfl_xor(sum, m);
      const float wk = p / sum;
      wks[n] = wk;
      float kc = wk * sigm(sim * conf_w[0] + conf_b[0]);
      #pragma unroll
      for (int m = 32; m > 0; m >>= 1) kc += __shfl_xor(kc, m);
      if (n == 0) *kxp = kc;
    }
    __syncthreads();

    // memory read: kx[d] = sg * sum_n wk[n] * MkT[b][d][n]
    {
      const int d = tid >> 2, q = tid & 3;
      const float* mr = MkT + (size_t)b * 4096 + d * 64 + q * 16;
      const float* wr = wks + q * 16;
      float a = 0.0f;
      #pragma unroll
      for (int i = 0; i < 4; ++i) {
        const float4 m4 = *(const float4*)(mr + 4 * i);
        const float4 w4 = *(const float4*)(wr + 4 * i);
        a += m4.x * w4.x + m4.y * w4.y + m4.z * w4.z + m4.w * w4.w;
      }
      psum[tid] = a;
    }
    __syncthreads();
    if (tid < 64) {
      kxs[tid] = (*sgp) * (psum[tid * 4] + psum[tid * 4 + 1] + psum[tid * 4 + 2] + psum[tid * 4 + 3]);
    } else if (tid == 64) {
      kxs[64] = (*sgp) * (*kxp);
    }
    __syncthreads();

    // Gkx(t+1)[b][j] = sum_{k<65} kxs[k] * WT[k][j]; thread -> 8 consecutive j
    {
      const int j0 = tid * 8;
      float a[8];
      #pragma unroll
      for (int i = 0; i < 8; ++i) a[i] = 0.0f;
      for (int k = 0; k < 65; ++k) {
        const float xk = kxs[k];
        const float4 w0 = *(const float4*)(WT + (size_t)k * 2048 + j0);
        const float4 w1 = *(const float4*)(WT + (size_t)k * 2048 + j0 + 4);
        a[0] += xk * w0.x; a[1] += xk * w0.y; a[2] += xk * w0.z; a[3] += xk * w0.w;
        a[4] += xk * w1.x; a[5] += xk * w1.y; a[6] += xk * w1.z; a[7] += xk * w1.w;
      }
      *(float4*)(Gkout + (size_t)b * 2048 + j0)     = *(float4*)&a[0];
      *(float4*)(Gkout + (size_t)b * 2048 + j0 + 4) = *(float4*)&a[4];
    }
  } else {
    // ===== gates role: Gh(t+1) slice =====
    if (t == 63) return;
    const int g  = bid - 256;
    const int bt = g >> 4, jt = g & 15;
    const int b0 = bt * 16;
    float* hs2T = smem;                    // [512][18] -> 9216 floats

    // recompute h(t) for 16 batches (redundant, deterministic)
    for (int i = tid; i < 8192; i += 256) {
      const int bl = i >> 9, j = i & 511;
      const float* ghp = Ghin + (size_t)(b0 + bl) * 2048;
      const float* gkp = Gkin + (size_t)(b0 + bl) * 2048;
      const float gi = bsum[j]        + ghp[j]        + gkp[j];
      const float gf = bsum[512 + j]  + ghp[512 + j]  + gkp[512 + j];
      const float gg = bsum[1024 + j] + ghp[1024 + j] + gkp[1024 + j];
      const float go = bsum[1536 + j] + ghp[1536 + j] + gkp[1536 + j];
      const float c2 = sigm(gf) * Cin[(size_t)(b0 + bl) * 512 + j] + sigm(gi) * tanhf(gg);
      hs2T[j * 18 + bl] = sigm(go) * tanhf(c2);
    }
    __syncthreads();

    // Gh(t+1)[b0..b0+16][jt*128..+128) = hs2T^T @ WT[65..577)
    {
      const int tj = tid & 31, tb = tid >> 5;      // 32 j-lanes x (8 grp x 2 b)
      const int j0 = jt * 128 + tj * 4;
      float acc[2][4];
      #pragma unroll
      for (int i = 0; i < 2; ++i) { acc[i][0]=0.f; acc[i][1]=0.f; acc[i][2]=0.f; acc[i][3]=0.f; }
      const float* wp = WT + (size_t)65 * 2048 + j0;
      #pragma unroll 4
      for (int k = 0; k < 512; ++k) {
        const float4 w = *(const float4*)(wp + (size_t)k * 2048);
        const float2 x = *(const float2*)(&hs2T[k * 18 + tb * 2]);
        acc[0][0] += x.x * w.x; acc[0][1] += x.x * w.y; acc[0][2] += x.x * w.z; acc[0][3] += x.x * w.w;
        acc[1][0] += x.y * w.x; acc[1][1] += x.y * w.y; acc[1][2] += x.y * w.z; acc[1][3] += x.y * w.w;
      }
      #pragma unroll
      for (int i = 0; i < 2; ++i) {
        float4 r; r.x = acc[i][0]; r.y = acc[i][1]; r.z = acc[i][2]; r.w = acc[i][3];
        *(float4*)(Ghout + (size_t)(b0 + tb * 2 + i) * 2048 + j0) = r;
      }
    }
  }
}

// ---------------------------------------------------------------------------
extern "C" void kernel_launch(void* const* d_in, const int* in_sizes, int n_in,
                              void* d_out, int out_size, void* d_ws, size_t ws_size,
                              hipStream_t stream) {
  const float* images = (const float*)d_in[0];
  const float* w1     = (const float*)d_in[1];
  const float* b1     = (const float*)d_in[2];
  const float* w2     = (const float*)d_in[3];
  const float* b2     = (const float*)d_in[4];
  const float* w3     = (const float*)d_in[5];
  const float* b3     = (const float*)d_in[6];
  const float* ew     = (const float*)d_in[7];
  const float* eb     = (const float*)d_in[8];
  const float* w_ih   = (const float*)d_in[9];
  const float* w_hh   = (const float*)d_in[10];
  const float* b_ih   = (const float*)d_in[11];
  const float* b_hh   = (const float*)d_in[12];
  const float* out_w  = (const float*)d_in[13];
  const float* out_b  = (const float*)d_in[14];
  const float* gate_w = (const float*)d_in[15];
  const float* gate_b = (const float*)d_in[16];
  const float* key_w  = (const float*)d_in[17];
  const float* key_b  = (const float*)d_in[18];
  const float* conf_w = (const float*)d_in[19];
  const float* conf_b = (const float*)d_in[20];
  float* o_ptr = (float*)d_out;
  float* ws    = (float*)d_ws;

  // ws layout (floats)
  float* WT     = ws;                  // 1,187,840
  float* bsum   = ws + 1187840;        // 2,048
  float* w1T    = ws + 1189888;        // 1,536
  float* w2T    = ws + 1191424;        // 32,768
  float* w3T    = ws + 1224192;        // 65,536
  float* ewT    = ws + 1289728;        // 16,384
  float* z_all  = ws + 1306112;        // 1,048,576
  float* z_gram = ws + 2354688;        // 1,048,576
  float* MkT    = ws + 3403264;        // 1,048,576
  float* Cb0    = ws + 4451840;        // 131,072
  float* Cb1    = ws + 4582912;        // 131,072
  float* Gh0    = ws + 4713984;        // 524,288
  float* Gh1    = ws + 5238272;        // 524,288
  float* Gk0    = ws + 5762560;        // 524,288
  float* Gk1    = ws + 6286848;        // 524,288
  const size_t baseF = 6811136;        // c1g starts here
  float* c1g = ws + baseF;
  const size_t availF = (ws_size / 4 > baseF) ? (ws_size / 4 - baseF) : 0;
  long chunkL = (long)(availF / 7680ull);
  int chunk = (chunkL > 16384) ? 16384 : (int)chunkL;

  // zero: G(0) buffers (consumed at t=0), C(-1) buffer (Cb1), MkT (finite garbage)
  hipMemsetAsync(Gh0, 0, 524288 * sizeof(float), stream);
  hipMemsetAsync(Gk0, 0, 524288 * sizeof(float), stream);
  hipMemsetAsync(Cb1, 0, 131072 * sizeof(float), stream);
  hipMemsetAsync(MkT, 0, 1048576 * sizeof(float), stream);

  prep_kernel<<<(PREP_N + 255) / 256, 256, 0, stream>>>(
      w_ih, w_hh, b_ih, b_hh, w1, w2, w3, ew, WT, bsum, w1T, w2T, w3T, ewT);

  if (chunk >= 2048) {
    for (int s0 = 0; s0 < 16384; s0 += chunk) {
      const int n = (16384 - s0 < chunk) ? (16384 - s0) : chunk;
      conv1_kernel<<<n, ENT, 0, stream>>>(images, w1T, b1, c1g, s0);
      enc2_kernel<<<n, ENT, 0, stream>>>(c1g, w2T, b2, w3T, b3, ewT, eb, z_all, s0);
    }
  } else {
    encoder_kernel<<<16384, ENT, 0, stream>>>(images, w1T, b1, w2T, b2, w3T, b3, ewT, eb, z_all);
  }

  gram_kernel<<<256, 256, 0, stream>>>(z_all, z_gram);

  for (int t = 0; t < 64; ++t) {
    float* Ghin  = (t & 1) ? Gh1 : Gh0;
    float* Ghout = (t & 1) ? Gh0 : Gh1;
    float* Gkin  = (t & 1) ? Gk1 : Gk0;
    float* Gkout = (t & 1) ? Gk0 : Gk1;
    float* Cin   = (t & 1) ? Cb1 : Cb1;     // C(t-1) buffer: (t-1)&1
    float* Cout  = (t & 1) ? Cb1 : Cb0;
    // fix buffer parity explicitly:
    Cin  = ((t & 1) == 0) ? Cb1 : Cb0;      // (t-1)&1
    Cout = ((t & 1) == 0) ? Cb0 : Cb1;      // t&1
    scan_pipe_kernel<<<512, 256, 0, stream>>>(
        t, Ghin, Ghout, Gkin, Gkout, Cin, Cout, WT, bsum, z_gram, MkT, o_ptr,
        out_w, out_b, gate_w, gate_b, key_w, key_b, conf_w, conf_b);
  }
}